// Round 1
// baseline (1424.447 us; speedup 1.0000x reference)
//
#include <hip/hip_runtime.h>
#include <math.h>

#define B_  4
#define T_  1024
#define C_  1024
#define H_  16
#define HS_ 64
#define N3_ 3072
#define SCALE_ 0.125f

__device__ __forceinline__ float sigmoidf_(float x){ return 1.0f/(1.0f + __expf(-x)); }
__device__ __forceinline__ float softplusf_(float x){ return fmaxf(x, 0.0f) + log1pf(__expf(-fabsf(x))); }

// ---------------------------------------------------------------------------
// GEMM 1: qkv = x @ W_attn + b_attn, scattered into Q/K/V [B,H,T,hs]
// M=4096, N=3072, K=1024. 128x128 tile, 256 threads, 8x8 per thread.
// ---------------------------------------------------------------------------
__global__ __launch_bounds__(256) void gemm_qkv_k(
    const float* __restrict__ x, const float* __restrict__ W,
    const float* __restrict__ bias,
    float* __restrict__ Q, float* __restrict__ K, float* __restrict__ V)
{
    __shared__ float As[8][128];
    __shared__ float Bs[8][128];
    const int tx = threadIdx.x, ty = threadIdx.y;
    const int tid = ty*16 + tx;
    const int m0 = blockIdx.y * 128;
    const int n0 = blockIdx.x * 128;
    float acc[8][8];
    #pragma unroll
    for (int i=0;i<8;i++){
        #pragma unroll
        for (int j=0;j<8;j++) acc[i][j]=0.f;
    }
    const int arow = tid>>1, aseg = tid&1;
    const int brow = tid>>5, bseg = tid&31;
    for (int k0=0; k0<1024; k0+=8) {
        __syncthreads();
        float4 av = *(const float4*)(x + (size_t)(m0+arow)*1024 + k0 + aseg*4);
        As[aseg*4+0][arow]=av.x; As[aseg*4+1][arow]=av.y;
        As[aseg*4+2][arow]=av.z; As[aseg*4+3][arow]=av.w;
        float4 bv = *(const float4*)(W + (size_t)(k0+brow)*3072 + n0 + bseg*4);
        *(float4*)(&Bs[brow][bseg*4]) = bv;
        __syncthreads();
        #pragma unroll
        for (int kk=0;kk<8;kk++){
            float a[8], b[8];
            *(float4*)(a)   = *(const float4*)(&As[kk][ty*4]);
            *(float4*)(a+4) = *(const float4*)(&As[kk][64+ty*4]);
            *(float4*)(b)   = *(const float4*)(&Bs[kk][tx*4]);
            *(float4*)(b+4) = *(const float4*)(&Bs[kk][64+tx*4]);
            #pragma unroll
            for (int i=0;i<8;i++){
                #pragma unroll
                for (int j=0;j<8;j++)
                    acc[i][j] = fmaf(a[i], b[j], acc[i][j]);
            }
        }
    }
    #pragma unroll
    for (int i=0;i<8;i++){
        int mloc = (i<4)? (ty*4+i) : (64+ty*4+(i-4));
        int m = m0 + mloc;
        int bb = m >> 10, t = m & 1023;
        #pragma unroll
        for (int jj=0;jj<2;jj++){
            int n = n0 + ((jj==0)? tx*4 : 64+tx*4);
            float4 v;
            v.x = acc[i][jj*4+0] + bias[n+0];
            v.y = acc[i][jj*4+1] + bias[n+1];
            v.z = acc[i][jj*4+2] + bias[n+2];
            v.w = acc[i][jj*4+3] + bias[n+3];
            int which = n >> 10, c = n & 1023;
            int h = c >> 6, d = c & 63;
            float* dst = (which==0)?Q:((which==1)?K:V);
            *(float4*)(dst + (size_t)(((bb*H_+h)*T_ + t))*HS_ + d) = v;
        }
    }
}

// ---------------------------------------------------------------------------
// Attention pass A+B: per (b,h,64-query tile): online softmax (m,l), then
// recompute scores and accumulate column sums of probs into colp.
// ---------------------------------------------------------------------------
__global__ __launch_bounds__(256) void attn_stats_k(
    const float* __restrict__ Q, const float* __restrict__ K,
    float* __restrict__ rowm, float* __restrict__ rowl,
    float* __restrict__ colp)
{
    __shared__ float QsT[64][68];
    __shared__ float KsT[64][68];
    __shared__ float colacc[64];
    const int g  = blockIdx.x & 15;
    const int bh = blockIdx.x >> 4;
    const int tid = threadIdx.x;
    const int tx = tid & 15, ty = tid >> 4;
    const float* Qb = Q + (size_t)bh*T_*HS_;
    const float* Kb = K + (size_t)bh*T_*HS_;

    #pragma unroll
    for (int i=0;i<4;i++){
        int idx = i*256 + tid;
        int qi = idx >> 4, dseg = idx & 15;
        float4 v = *(const float4*)(Qb + (size_t)(g*64+qi)*HS_ + dseg*4);
        QsT[dseg*4+0][qi]=v.x; QsT[dseg*4+1][qi]=v.y;
        QsT[dseg*4+2][qi]=v.z; QsT[dseg*4+3][qi]=v.w;
    }
    float m_run[4], l_run[4];
    #pragma unroll
    for (int i=0;i<4;i++){ m_run[i]=-1e30f; l_run[i]=0.f; }

    // phase A: online (m,l)
    for (int kt=0; kt<=g; kt++){
        __syncthreads();
        #pragma unroll
        for (int i=0;i<4;i++){
            int idx = i*256 + tid;
            int ki = idx >> 4, dseg = idx & 15;
            float4 v = *(const float4*)(Kb + (size_t)(kt*64+ki)*HS_ + dseg*4);
            KsT[dseg*4+0][ki]=v.x; KsT[dseg*4+1][ki]=v.y;
            KsT[dseg*4+2][ki]=v.z; KsT[dseg*4+3][ki]=v.w;
        }
        __syncthreads();
        float acc[4][4];
        #pragma unroll
        for (int i=0;i<4;i++){ acc[i][0]=0.f;acc[i][1]=0.f;acc[i][2]=0.f;acc[i][3]=0.f; }
        for (int d=0; d<64; d++){
            float4 qv = *(const float4*)(&QsT[d][ty*4]);
            float4 kv = *(const float4*)(&KsT[d][tx*4]);
            const float* qa=(const float*)&qv; const float* ka=(const float*)&kv;
            #pragma unroll
            for (int iq=0;iq<4;iq++){
                #pragma unroll
                for (int ik=0;ik<4;ik++)
                    acc[iq][ik] = fmaf(qa[iq], ka[ik], acc[iq][ik]);
            }
        }
        #pragma unroll
        for (int iq=0;iq<4;iq++){
            float s[4];
            #pragma unroll
            for (int ik=0;ik<4;ik++){
                s[ik] = acc[iq][ik]*SCALE_;
                if (kt==g && (tx*4+ik) > (ty*4+iq)) s[ik] = -1e30f;
            }
            float tmax = fmaxf(fmaxf(s[0],s[1]),fmaxf(s[2],s[3]));
            #pragma unroll
            for (int off=1; off<16; off<<=1) tmax = fmaxf(tmax, __shfl_xor(tmax, off, 64));
            float mnew = fmaxf(m_run[iq], tmax);
            float psum = 0.f;
            #pragma unroll
            for (int ik=0;ik<4;ik++) psum += __expf(s[ik]-mnew);
            #pragma unroll
            for (int off=1; off<16; off<<=1) psum += __shfl_xor(psum, off, 64);
            l_run[iq] = l_run[iq]*__expf(m_run[iq]-mnew) + psum;
            m_run[iq] = mnew;
        }
    }
    if (tx==0){
        #pragma unroll
        for (int iq=0;iq<4;iq++){
            rowm[(size_t)bh*T_ + g*64 + ty*4+iq] = m_run[iq];
            rowl[(size_t)bh*T_ + g*64 + ty*4+iq] = l_run[iq];
        }
    }
    float invl[4];
    #pragma unroll
    for (int iq=0;iq<4;iq++) invl[iq] = 1.f/l_run[iq];

    // phase B: column sums of probs
    for (int kt=0; kt<=g; kt++){
        __syncthreads();
        #pragma unroll
        for (int i=0;i<4;i++){
            int idx = i*256 + tid;
            int ki = idx >> 4, dseg = idx & 15;
            float4 v = *(const float4*)(Kb + (size_t)(kt*64+ki)*HS_ + dseg*4);
            KsT[dseg*4+0][ki]=v.x; KsT[dseg*4+1][ki]=v.y;
            KsT[dseg*4+2][ki]=v.z; KsT[dseg*4+3][ki]=v.w;
        }
        if (tid<64) colacc[tid]=0.f;
        __syncthreads();
        float acc[4][4];
        #pragma unroll
        for (int i=0;i<4;i++){ acc[i][0]=0.f;acc[i][1]=0.f;acc[i][2]=0.f;acc[i][3]=0.f; }
        for (int d=0; d<64; d++){
            float4 qv = *(const float4*)(&QsT[d][ty*4]);
            float4 kv = *(const float4*)(&KsT[d][tx*4]);
            const float* qa=(const float*)&qv; const float* ka=(const float*)&kv;
            #pragma unroll
            for (int iq=0;iq<4;iq++){
                #pragma unroll
                for (int ik=0;ik<4;ik++)
                    acc[iq][ik] = fmaf(qa[iq], ka[ik], acc[iq][ik]);
            }
        }
        float csum[4] = {0.f,0.f,0.f,0.f};
        #pragma unroll
        for (int iq=0;iq<4;iq++){
            #pragma unroll
            for (int ik=0;ik<4;ik++){
                bool valid = (kt<g) || ((tx*4+ik) <= (ty*4+iq));
                if (valid){
                    float p = __expf(acc[iq][ik]*SCALE_ - m_run[iq])*invl[iq];
                    csum[ik] += p;
                }
            }
        }
        #pragma unroll
        for (int ik=0;ik<4;ik++) atomicAdd(&colacc[tx*4+ik], csum[ik]);
        __syncthreads();
        if (tid<64) atomicAdd(&colp[(size_t)bh*T_ + kt*64 + tid], colacc[tid]);
    }
}

// ---------------------------------------------------------------------------
// Attention pass C: pw = p*lif_w; D = rowsum(pw); Yh = (pw @ V)/(D+1e-8);
// then column sums of normalized mod into racc.
// ---------------------------------------------------------------------------
__global__ __launch_bounds__(256) void attn_apply_k(
    const float* __restrict__ Q, const float* __restrict__ K,
    const float* __restrict__ V,
    const float* __restrict__ rowm, const float* __restrict__ rowl,
    const float* __restrict__ colp, const float* __restrict__ refr,
    const float* __restrict__ threshold, const float* __restrict__ leak,
    const float* __restrict__ steepness, const float* __restrict__ ref_strength,
    const float* __restrict__ cross_w,
    float* __restrict__ Yh, float* __restrict__ racc)
{
    __shared__ float QsT[64][68];
    __shared__ float KM[64][68];   // K-tile during scores, then mod-tile (MsT) for PV
    __shared__ float Vs[64][68];
    __shared__ float ebase[64];
    __shared__ float colacc[64];
    const int g  = blockIdx.x & 15;
    const int bh = blockIdx.x >> 4;
    const int b  = bh >> 4, h = bh & 15;
    const int tid = threadIdx.x;
    const int tx = tid & 15, ty = tid >> 4;
    const float* Qb = Q + (size_t)bh*T_*HS_;
    const float* Kb = K + (size_t)bh*T_*HS_;
    const float* Vb = V + (size_t)bh*T_*HS_;

    const float thr = fabsf(threshold[h])*0.1f;
    const float lk  = sigmoidf_(leak[h]);
    const float st  = softplusf_(steepness[h]);
    const float spr = softplusf_(ref_strength[h]);
    const float cw  = sigmoidf_(cross_w[h]);

    #pragma unroll
    for (int i=0;i<4;i++){
        int idx = i*256 + tid;
        int qi = idx >> 4, dseg = idx & 15;
        float4 v = *(const float4*)(Qb + (size_t)(g*64+qi)*HS_ + dseg*4);
        QsT[dseg*4+0][qi]=v.x; QsT[dseg*4+1][qi]=v.y;
        QsT[dseg*4+2][qi]=v.z; QsT[dseg*4+3][qi]=v.w;
    }
    float mr[4], invl[4];
    #pragma unroll
    for (int iq=0;iq<4;iq++){
        mr[iq]  = rowm[(size_t)bh*T_ + g*64 + ty*4+iq];
        invl[iq]= 1.f/rowl[(size_t)bh*T_ + g*64 + ty*4+iq];
    }

    float yacc[4][4];
    #pragma unroll
    for (int i=0;i<4;i++){ yacc[i][0]=0.f;yacc[i][1]=0.f;yacc[i][2]=0.f;yacc[i][3]=0.f; }
    float Dpart[4] = {0.f,0.f,0.f,0.f};

    // phase 1: unnormalized PV + D
    for (int kt=0; kt<=g; kt++){
        __syncthreads();
        #pragma unroll
        for (int i=0;i<4;i++){
            int idx = i*256 + tid;
            int ki = idx >> 4, dseg = idx & 15;
            float4 kv = *(const float4*)(Kb + (size_t)(kt*64+ki)*HS_ + dseg*4);
            KM[dseg*4+0][ki]=kv.x; KM[dseg*4+1][ki]=kv.y;
            KM[dseg*4+2][ki]=kv.z; KM[dseg*4+3][ki]=kv.w;
            float4 vv = *(const float4*)(Vb + (size_t)(kt*64+ki)*HS_ + dseg*4);
            *(float4*)(&Vs[ki][dseg*4]) = vv;
        }
        if (tid<64)
            ebase[tid] = thr + spr*colp[(size_t)bh*T_ + kt*64 + tid]*(1.0f/T_)
                             + cw*refr[(size_t)b*T_ + kt*64 + tid];
        __syncthreads();
        float acc[4][4];
        #pragma unroll
        for (int i=0;i<4;i++){ acc[i][0]=0.f;acc[i][1]=0.f;acc[i][2]=0.f;acc[i][3]=0.f; }
        for (int d=0; d<64; d++){
            float4 qv = *(const float4*)(&QsT[d][ty*4]);
            float4 kv = *(const float4*)(&KM[d][tx*4]);
            const float* qa=(const float*)&qv; const float* ka=(const float*)&kv;
            #pragma unroll
            for (int iq=0;iq<4;iq++){
                #pragma unroll
                for (int ik=0;ik<4;ik++)
                    acc[iq][ik] = fmaf(qa[iq], ka[ik], acc[iq][ik]);
            }
        }
        __syncthreads();   // done reading KM as K-tile
        #pragma unroll
        for (int iq=0;iq<4;iq++){
            #pragma unroll
            for (int ik=0;ik<4;ik++){
                bool valid = (kt<g) || ((tx*4+ik) <= (ty*4+iq));
                float pw = 0.f;
                if (valid){
                    float p = __expf(acc[iq][ik]*SCALE_ - mr[iq])*invl[iq];
                    float fire = sigmoidf_(st*(p - ebase[tx*4+ik]));
                    float w = lk + (1.f-lk)*fire;
                    pw = p*w;
                    Dpart[iq] += pw;
                }
                KM[tx*4+ik][ty*4+iq] = pw;   // MsT[ki][qi]
            }
        }
        __syncthreads();
        for (int kk=0; kk<64; kk++){
            float4 mv = *(const float4*)(&KM[kk][ty*4]);
            float4 vv = *(const float4*)(&Vs[kk][tx*4]);
            const float* ma=(const float*)&mv; const float* va=(const float*)&vv;
            #pragma unroll
            for (int iq=0;iq<4;iq++){
                #pragma unroll
                for (int jd=0;jd<4;jd++)
                    yacc[iq][jd] = fmaf(ma[iq], va[jd], yacc[iq][jd]);
            }
        }
    }
    float invD[4];
    #pragma unroll
    for (int iq=0;iq<4;iq++){
        float D = Dpart[iq];
        #pragma unroll
        for (int off=1; off<16; off<<=1) D += __shfl_xor(D, off, 64);
        invD[iq] = 1.f/(D + 1e-8f);
    }
    #pragma unroll
    for (int iq=0;iq<4;iq++){
        float4 v;
        v.x = yacc[iq][0]*invD[iq]; v.y = yacc[iq][1]*invD[iq];
        v.z = yacc[iq][2]*invD[iq]; v.w = yacc[iq][3]*invD[iq];
        *(float4*)(Yh + (size_t)(bh*T_ + g*64 + ty*4+iq)*HS_ + tx*4) = v;
    }

    // phase 2: column sums of normalized mod -> racc
    for (int kt=0; kt<=g; kt++){
        __syncthreads();
        #pragma unroll
        for (int i=0;i<4;i++){
            int idx = i*256 + tid;
            int ki = idx >> 4, dseg = idx & 15;
            float4 kv = *(const float4*)(Kb + (size_t)(kt*64+ki)*HS_ + dseg*4);
            KM[dseg*4+0][ki]=kv.x; KM[dseg*4+1][ki]=kv.y;
            KM[dseg*4+2][ki]=kv.z; KM[dseg*4+3][ki]=kv.w;
        }
        if (tid<64){
            ebase[tid] = thr + spr*colp[(size_t)bh*T_ + kt*64 + tid]*(1.0f/T_)
                             + cw*refr[(size_t)b*T_ + kt*64 + tid];
            colacc[tid]=0.f;
        }
        __syncthreads();
        float acc[4][4];
        #pragma unroll
        for (int i=0;i<4;i++){ acc[i][0]=0.f;acc[i][1]=0.f;acc[i][2]=0.f;acc[i][3]=0.f; }
        for (int d=0; d<64; d++){
            float4 qv = *(const float4*)(&QsT[d][ty*4]);
            float4 kv = *(const float4*)(&KM[d][tx*4]);
            const float* qa=(const float*)&qv; const float* ka=(const float*)&kv;
            #pragma unroll
            for (int iq=0;iq<4;iq++){
                #pragma unroll
                for (int ik=0;ik<4;ik++)
                    acc[iq][ik] = fmaf(qa[iq], ka[ik], acc[iq][ik]);
            }
        }
        float csum[4] = {0.f,0.f,0.f,0.f};
        #pragma unroll
        for (int iq=0;iq<4;iq++){
            #pragma unroll
            for (int ik=0;ik<4;ik++){
                bool valid = (kt<g) || ((tx*4+ik) <= (ty*4+iq));
                if (valid){
                    float p = __expf(acc[iq][ik]*SCALE_ - mr[iq])*invl[iq];
                    float fire = sigmoidf_(st*(p - ebase[tx*4+ik]));
                    float w = lk + (1.f-lk)*fire;
                    csum[ik] += p*w*invD[iq];
                }
            }
        }
        #pragma unroll
        for (int ik=0;ik<4;ik++) atomicAdd(&colacc[tx*4+ik], csum[ik]);
        __syncthreads();
        if (tid<64) atomicAdd(&racc[(size_t)b*T_ + kt*64 + tid], colacc[tid]);
    }
}

// ---------------------------------------------------------------------------
// GEMM 2: out = gather(Yh) @ W_proj + b_proj.  M=4096, N=1024, K=1024.
// ---------------------------------------------------------------------------
__global__ __launch_bounds__(256) void gemm_proj_k(
    const float* __restrict__ Yh, const float* __restrict__ W,
    const float* __restrict__ bias, float* __restrict__ out)
{
    __shared__ float As[8][128];
    __shared__ float Bs[8][128];
    const int tx = threadIdx.x, ty = threadIdx.y;
    const int tid = ty*16 + tx;
    const int m0 = blockIdx.y * 128;
    const int n0 = blockIdx.x * 128;
    float acc[8][8];
    #pragma unroll
    for (int i=0;i<8;i++){
        #pragma unroll
        for (int j=0;j<8;j++) acc[i][j]=0.f;
    }
    const int arow = tid>>1, aseg = tid&1;
    const int brow = tid>>5, bseg = tid&31;
    const int m = m0 + arow;
    const int bb = m >> 10, t = m & 1023;
    for (int k0=0; k0<1024; k0+=8) {
        __syncthreads();
        int k = k0 + aseg*4;
        int h = k >> 6, d = k & 63;
        float4 av = *(const float4*)(Yh + (size_t)((bb*H_+h)*T_ + t)*HS_ + d);
        As[aseg*4+0][arow]=av.x; As[aseg*4+1][arow]=av.y;
        As[aseg*4+2][arow]=av.z; As[aseg*4+3][arow]=av.w;
        float4 bv = *(const float4*)(W + (size_t)(k0+brow)*1024 + n0 + bseg*4);
        *(float4*)(&Bs[brow][bseg*4]) = bv;
        __syncthreads();
        #pragma unroll
        for (int kk=0;kk<8;kk++){
            float a[8], b[8];
            *(float4*)(a)   = *(const float4*)(&As[kk][ty*4]);
            *(float4*)(a+4) = *(const float4*)(&As[kk][64+ty*4]);
            *(float4*)(b)   = *(const float4*)(&Bs[kk][tx*4]);
            *(float4*)(b+4) = *(const float4*)(&Bs[kk][64+tx*4]);
            #pragma unroll
            for (int i=0;i<8;i++){
                #pragma unroll
                for (int j=0;j<8;j++)
                    acc[i][j] = fmaf(a[i], b[j], acc[i][j]);
            }
        }
    }
    #pragma unroll
    for (int i=0;i<8;i++){
        int mm = m0 + ((i<4)? (ty*4+i) : (64+ty*4+(i-4)));
        #pragma unroll
        for (int jj=0;jj<2;jj++){
            int n = n0 + ((jj==0)? tx*4 : 64+tx*4);
            float4 v;
            v.x = acc[i][jj*4+0] + bias[n+0];
            v.y = acc[i][jj*4+1] + bias[n+1];
            v.z = acc[i][jj*4+2] + bias[n+2];
            v.w = acc[i][jj*4+3] + bias[n+3];
            *(float4*)(out + (size_t)mm*1024 + n) = v;
        }
    }
}

__global__ __launch_bounds__(256) void finish_refr_k(
    const float* __restrict__ racc, float* __restrict__ out)
{
    int i = blockIdx.x*256 + threadIdx.x;
    if (i < B_*T_) out[i] = racc[i] * (1.0f/(H_*T_));
}

// ---------------------------------------------------------------------------
extern "C" void kernel_launch(void* const* d_in, const int* in_sizes, int n_in,
                              void* d_out, int out_size, void* d_ws, size_t ws_size,
                              hipStream_t stream) {
    (void)in_sizes; (void)n_in; (void)out_size; (void)ws_size;
    const float* x          = (const float*)d_in[0];
    const float* refr       = (const float*)d_in[1];
    const float* W_attn     = (const float*)d_in[2];
    const float* b_attn     = (const float*)d_in[3];
    const float* W_proj     = (const float*)d_in[4];
    const float* b_proj     = (const float*)d_in[5];
    const float* threshold  = (const float*)d_in[6];
    const float* leak       = (const float*)d_in[7];
    const float* steepness  = (const float*)d_in[8];
    const float* ref_strength=(const float*)d_in[9];
    const float* cross_w    = (const float*)d_in[10];
    float* out = (float*)d_out;

    float* ws = (float*)d_ws;
    const size_t QKV = (size_t)B_*H_*T_*HS_;      // 4,194,304
    const size_t BHT = (size_t)B_*H_*T_;          // 65,536
    float* Q    = ws;
    float* K    = Q + QKV;
    float* V    = K + QKV;
    float* Yh   = V + QKV;
    float* rowm = Yh + QKV;
    float* rowl = rowm + BHT;
    float* colp = rowl + BHT;
    float* racc = colp + BHT;

    hipMemsetAsync(colp, 0, BHT*sizeof(float), stream);
    hipMemsetAsync(racc, 0, (size_t)B_*T_*sizeof(float), stream);

    gemm_qkv_k<<<dim3(24,32), dim3(16,16), 0, stream>>>(x, W_attn, b_attn, Q, K, V);
    attn_stats_k<<<dim3(B_*H_*16), dim3(256), 0, stream>>>(Q, K, rowm, rowl, colp);
    attn_apply_k<<<dim3(B_*H_*16), dim3(256), 0, stream>>>(
        Q, K, V, rowm, rowl, colp, refr,
        threshold, leak, steepness, ref_strength, cross_w, Yh, racc);
    gemm_proj_k<<<dim3(8,32), dim3(16,16), 0, stream>>>(Yh, W_proj, b_proj, out);
    finish_refr_k<<<dim3(16), dim3(256), 0, stream>>>(racc, out + (size_t)B_*T_*C_);
}

// Round 2
// 334.225 us; speedup vs baseline: 4.2619x; 4.2619x over previous
//
#include <hip/hip_runtime.h>
#include <math.h>

#define B_  4
#define T_  1024
#define C_  1024
#define H_  16
#define HS_ 64
#define SCALE_ 0.125f

typedef _Float16 f16;
typedef _Float16 f16x8 __attribute__((ext_vector_type(8)));
typedef float f32x4 __attribute__((ext_vector_type(4)));

#define MFMA16(a,b,c) __builtin_amdgcn_mfma_f32_16x16x32_f16(a,b,c,0,0,0)

__device__ __forceinline__ float qmax_(float v){
    v = fmaxf(v, __shfl_xor(v,1,64)); v = fmaxf(v, __shfl_xor(v,2,64));
    v = fmaxf(v, __shfl_xor(v,4,64)); v = fmaxf(v, __shfl_xor(v,8,64));
    return v;
}
__device__ __forceinline__ float qsum_(float v){
    v += __shfl_xor(v,1,64); v += __shfl_xor(v,2,64);
    v += __shfl_xor(v,4,64); v += __shfl_xor(v,8,64);
    return v;
}
__device__ __forceinline__ float sigmoidf_(float x){ return 1.0f/(1.0f + __expf(-x)); }
__device__ __forceinline__ float softplusf_(float x){ return fmaxf(x, 0.0f) + log1pf(__expf(-fabsf(x))); }

// ---------------------------------------------------------------------------
// fp32 -> f16 elementwise (8 per thread)
// ---------------------------------------------------------------------------
__global__ __launch_bounds__(256) void conv_f16_k(
    const float* __restrict__ in, f16* __restrict__ out, int n8)
{
    int i = blockIdx.x*256 + threadIdx.x;
    if (i < n8){
        const float4* p = (const float4*)in + (size_t)i*2;
        float4 a = p[0], b = p[1];
        f16x8 o;
        o[0]=(f16)a.x; o[1]=(f16)a.y; o[2]=(f16)a.z; o[3]=(f16)a.w;
        o[4]=(f16)b.x; o[5]=(f16)b.y; o[6]=(f16)b.z; o[7]=(f16)b.w;
        *((f16x8*)out + i) = o;
    }
}

// ---------------------------------------------------------------------------
// out[n][k] = (f16) in[k][n]   (in: K x N fp32)
// ---------------------------------------------------------------------------
__global__ __launch_bounds__(256) void transpose_f16_k(
    const float* __restrict__ in, f16* __restrict__ out, int K, int N)
{
    __shared__ float tl[32][33];
    const int n0 = blockIdx.x*32, k0 = blockIdx.y*32;
    const int c = threadIdx.x & 31, r4 = threadIdx.x >> 5;
    #pragma unroll
    for (int i=0;i<4;i++){
        int r = r4*4 + i;
        tl[r][c] = in[(size_t)(k0+r)*N + n0 + c];
    }
    __syncthreads();
    #pragma unroll
    for (int i=0;i<4;i++){
        int r = r4*4 + i;
        out[(size_t)(n0+r)*K + k0 + c] = (f16)tl[c][r];
    }
}

// ---------------------------------------------------------------------------
// GEMM qkv: A = x_h [4096][1024] f16, Bt = W_attn^T [3072][1024] f16.
// 128x128 tile, BK=32, 256 thr = 4 waves (2x2), each wave 64x64 via 16 MFMA.
// Epilogue: +bias, scatter f16 -> Qh/Kh [bh][t][d], Vt [bh][d][t].
// ---------------------------------------------------------------------------
__global__ __launch_bounds__(256) void gemm_qkv_k(
    const f16* __restrict__ A, const f16* __restrict__ Bt,
    const float* __restrict__ bias,
    f16* __restrict__ Qh, f16* __restrict__ Kh, f16* __restrict__ Vt)
{
    __shared__ __align__(16) f16 Al[4*1032];
    __shared__ __align__(16) f16 Bl[4*1032];
    const int tid = threadIdx.x;
    const int lane = tid & 63, wave = tid >> 6;
    const int lx = lane & 15, quad = lane >> 4;
    const int wm = wave & 1, wn = wave >> 1;
    const int m0 = blockIdx.y*128, n0 = blockIdx.x*128;
    f32x4 acc[4][4];
    #pragma unroll
    for (int i=0;i<4;i++){
        #pragma unroll
        for (int j=0;j<4;j++){ acc[i][j][0]=0.f;acc[i][j][1]=0.f;acc[i][j][2]=0.f;acc[i][j][3]=0.f; }
    }
    for (int k0=0; k0<1024; k0+=32){
        __syncthreads();
        #pragma unroll
        for (int i=0;i<2;i++){
            int g = i*256 + tid;
            int m = g >> 2, kc = g & 3;
            *(f16x8*)&Al[kc*1032 + m*8] = *(const f16x8*)(A  + (size_t)(m0+m)*1024 + k0 + kc*8);
            *(f16x8*)&Bl[kc*1032 + m*8] = *(const f16x8*)(Bt + (size_t)(n0+m)*1024 + k0 + kc*8);
        }
        __syncthreads();
        f16x8 af[4], bf[4];
        #pragma unroll
        for (int mt=0;mt<4;mt++) af[mt] = *(const f16x8*)&Al[quad*1032 + (wm*64+mt*16+lx)*8];
        #pragma unroll
        for (int nt=0;nt<4;nt++) bf[nt] = *(const f16x8*)&Bl[quad*1032 + (wn*64+nt*16+lx)*8];
        #pragma unroll
        for (int mt=0;mt<4;mt++){
            #pragma unroll
            for (int nt=0;nt<4;nt++)
                acc[mt][nt] = MFMA16(af[mt], bf[nt], acc[mt][nt]);
        }
    }
    #pragma unroll
    for (int mt=0;mt<4;mt++){
        #pragma unroll
        for (int nt=0;nt<4;nt++){
            int n = n0 + wn*64 + nt*16 + lx;
            int which = n >> 10, cc = n & 1023, h = cc >> 6, d = cc & 63;
            float bv = bias[n];
            #pragma unroll
            for (int r=0;r<4;r++){
                int m = m0 + wm*64 + mt*16 + quad*4 + r;
                int bb = m >> 10, t = m & 1023;
                int bh = bb*16 + h;
                float v = acc[mt][nt][r] + bv;
                if (which==0)      Qh[((size_t)bh*1024 + t)*64 + d] = (f16)v;
                else if (which==1) Kh[((size_t)bh*1024 + t)*64 + d] = (f16)v;
                else               Vt[((size_t)bh*64 + d)*1024 + t] = (f16)v;
            }
        }
    }
}

// ---------------------------------------------------------------------------
// GEMM proj: A = Yh [4096][1024] f16, Bt = W_proj^T [1024][1024] f16 -> out fp32
// ---------------------------------------------------------------------------
__global__ __launch_bounds__(256) void gemm_proj_k(
    const f16* __restrict__ A, const f16* __restrict__ Bt,
    const float* __restrict__ bias, float* __restrict__ out)
{
    __shared__ __align__(16) f16 Al[4*1032];
    __shared__ __align__(16) f16 Bl[4*1032];
    const int tid = threadIdx.x;
    const int lane = tid & 63, wave = tid >> 6;
    const int lx = lane & 15, quad = lane >> 4;
    const int wm = wave & 1, wn = wave >> 1;
    const int m0 = blockIdx.y*128, n0 = blockIdx.x*128;
    f32x4 acc[4][4];
    #pragma unroll
    for (int i=0;i<4;i++){
        #pragma unroll
        for (int j=0;j<4;j++){ acc[i][j][0]=0.f;acc[i][j][1]=0.f;acc[i][j][2]=0.f;acc[i][j][3]=0.f; }
    }
    for (int k0=0; k0<1024; k0+=32){
        __syncthreads();
        #pragma unroll
        for (int i=0;i<2;i++){
            int g = i*256 + tid;
            int m = g >> 2, kc = g & 3;
            *(f16x8*)&Al[kc*1032 + m*8] = *(const f16x8*)(A  + (size_t)(m0+m)*1024 + k0 + kc*8);
            *(f16x8*)&Bl[kc*1032 + m*8] = *(const f16x8*)(Bt + (size_t)(n0+m)*1024 + k0 + kc*8);
        }
        __syncthreads();
        f16x8 af[4], bf[4];
        #pragma unroll
        for (int mt=0;mt<4;mt++) af[mt] = *(const f16x8*)&Al[quad*1032 + (wm*64+mt*16+lx)*8];
        #pragma unroll
        for (int nt=0;nt<4;nt++) bf[nt] = *(const f16x8*)&Bl[quad*1032 + (wn*64+nt*16+lx)*8];
        #pragma unroll
        for (int mt=0;mt<4;mt++){
            #pragma unroll
            for (int nt=0;nt<4;nt++)
                acc[mt][nt] = MFMA16(af[mt], bf[nt], acc[mt][nt]);
        }
    }
    #pragma unroll
    for (int mt=0;mt<4;mt++){
        #pragma unroll
        for (int nt=0;nt<4;nt++){
            int n = n0 + wn*64 + nt*16 + lx;
            float bv = bias[n];
            #pragma unroll
            for (int r=0;r<4;r++){
                int m = m0 + wm*64 + mt*16 + quad*4 + r;
                out[(size_t)m*1024 + n] = acc[mt][nt][r] + bv;
            }
        }
    }
}

// ---------------------------------------------------------------------------
// attn_stats: per (bh, 64-q tile g): phase A online (m,l); phase B col sums.
// wave w handles queries w*16..w*16+15. Scores via 16x16x32 f16 MFMA.
// ---------------------------------------------------------------------------
__global__ __launch_bounds__(256) void attn_stats_k(
    const f16* __restrict__ Qh, const f16* __restrict__ Kh,
    float* __restrict__ rowm, float* __restrict__ rowl, float* __restrict__ colp)
{
    __shared__ __align__(16) f16 Kl[8*520];
    __shared__ float colacc[64];
    const int tid = threadIdx.x;
    const int lane = tid & 63, wave = tid >> 6;
    const int lx = lane & 15, quad = lane >> 4;
    const int g  = 15 - (blockIdx.x >> 6);
    const int bh = blockIdx.x & 63;
    const int qpos = wave*16 + quad*4;  // + r : query position within 64-tile

    const size_t qoff = ((size_t)bh*1024 + g*64 + wave*16 + lx)*64;
    f16x8 aq0 = *(const f16x8*)(Qh + qoff + quad*8);
    f16x8 aq1 = *(const f16x8*)(Qh + qoff + 32 + quad*8);

    float m_run[4], l_run[4];
    #pragma unroll
    for (int r=0;r<4;r++){ m_run[r]=-1e30f; l_run[r]=0.f; }

    for (int kt=0; kt<=g; kt++){
        __syncthreads();
        #pragma unroll
        for (int i=0;i<2;i++){
            int gi = i*256 + tid;
            int key = gi >> 3, kc = gi & 7;
            *(f16x8*)&Kl[kc*520 + key*8] =
                *(const f16x8*)(Kh + ((size_t)bh*1024 + kt*64 + key)*64 + kc*8);
        }
        __syncthreads();
        f32x4 sc[4];
        #pragma unroll
        for (int nt=0;nt<4;nt++){
            sc[nt][0]=0.f;sc[nt][1]=0.f;sc[nt][2]=0.f;sc[nt][3]=0.f;
            f16x8 b0 = *(const f16x8*)&Kl[quad*520     + (nt*16+lx)*8];
            f16x8 b1 = *(const f16x8*)&Kl[(4+quad)*520 + (nt*16+lx)*8];
            sc[nt] = MFMA16(aq0, b0, sc[nt]);
            sc[nt] = MFMA16(aq1, b1, sc[nt]);
        }
        const bool diag = (kt == g);
        #pragma unroll
        for (int r=0;r<4;r++){
            float s[4];
            #pragma unroll
            for (int nt=0;nt<4;nt++){
                float sv = sc[nt][r]*SCALE_;
                if (diag && (nt*16+lx) > (qpos + r)) sv = -1e30f;
                s[nt] = sv;
            }
            float tmax = fmaxf(fmaxf(s[0],s[1]),fmaxf(s[2],s[3]));
            tmax = qmax_(tmax);
            float mnew = fmaxf(m_run[r], tmax);
            float ps = __expf(s[0]-mnew)+__expf(s[1]-mnew)+__expf(s[2]-mnew)+__expf(s[3]-mnew);
            ps = qsum_(ps);
            l_run[r] = l_run[r]*__expf(m_run[r]-mnew) + ps;
            m_run[r] = mnew;
        }
    }
    if (lx == 0){
        #pragma unroll
        for (int r=0;r<4;r++){
            rowm[(size_t)bh*1024 + g*64 + qpos + r] = m_run[r];
            rowl[(size_t)bh*1024 + g*64 + qpos + r] = l_run[r];
        }
    }
    float invl[4];
    #pragma unroll
    for (int r=0;r<4;r++) invl[r] = 1.f/l_run[r];

    // phase B: column sums of p
    for (int kt=0; kt<=g; kt++){
        __syncthreads();
        #pragma unroll
        for (int i=0;i<2;i++){
            int gi = i*256 + tid;
            int key = gi >> 3, kc = gi & 7;
            *(f16x8*)&Kl[kc*520 + key*8] =
                *(const f16x8*)(Kh + ((size_t)bh*1024 + kt*64 + key)*64 + kc*8);
        }
        if (tid < 64) colacc[tid] = 0.f;
        __syncthreads();
        f32x4 sc[4];
        #pragma unroll
        for (int nt=0;nt<4;nt++){
            sc[nt][0]=0.f;sc[nt][1]=0.f;sc[nt][2]=0.f;sc[nt][3]=0.f;
            f16x8 b0 = *(const f16x8*)&Kl[quad*520     + (nt*16+lx)*8];
            f16x8 b1 = *(const f16x8*)&Kl[(4+quad)*520 + (nt*16+lx)*8];
            sc[nt] = MFMA16(aq0, b0, sc[nt]);
            sc[nt] = MFMA16(aq1, b1, sc[nt]);
        }
        const bool diag = (kt == g);
        float csum[4] = {0.f,0.f,0.f,0.f};
        #pragma unroll
        for (int r=0;r<4;r++){
            #pragma unroll
            for (int nt=0;nt<4;nt++){
                bool valid = !diag || ((nt*16+lx) <= (qpos + r));
                if (valid) csum[nt] += __expf(sc[nt][r]*SCALE_ - m_run[r]) * invl[r];
            }
        }
        #pragma unroll
        for (int nt=0;nt<4;nt++){
            float v = csum[nt];
            v += __shfl_xor(v,16,64); v += __shfl_xor(v,32,64);
            if (quad == 0) atomicAdd(&colacc[nt*16+lx], v);
        }
        __syncthreads();
        if (tid < 64) atomicAdd(&colp[(size_t)bh*1024 + kt*64 + tid], colacc[tid]);
    }
}

// ---------------------------------------------------------------------------
// attn_apply: phase 1: pw = p*lif_w, D rowsum, Y = (pw@V)/(D+1e-8) -> Yh f16;
// phase 2: column sums of mod = pw/D -> racc (atomic fp32).
// ---------------------------------------------------------------------------
__global__ __launch_bounds__(256) void attn_apply_k(
    const f16* __restrict__ Qh, const f16* __restrict__ Kh, const f16* __restrict__ Vt,
    const float* __restrict__ rowm, const float* __restrict__ rowl,
    const float* __restrict__ colp, const float* __restrict__ refr,
    const float* __restrict__ threshold, const float* __restrict__ leak,
    const float* __restrict__ steepness, const float* __restrict__ ref_strength,
    const float* __restrict__ cross_w,
    f16* __restrict__ Yh, float* __restrict__ racc)
{
    __shared__ __align__(16) f16 Kl[8*520];
    __shared__ __align__(16) f16 Vl[8*520];
    __shared__ __align__(16) f16 Pl[4][16*72];
    __shared__ float ebase[64];
    __shared__ float colacc[64];
    const int tid = threadIdx.x;
    const int lane = tid & 63, wave = tid >> 6;
    const int lx = lane & 15, quad = lane >> 4;
    const int g  = 15 - (blockIdx.x >> 6);
    const int bh = blockIdx.x & 63;
    const int b  = bh >> 4, h = bh & 15;
    const int qpos = wave*16 + quad*4;

    const float thr = fabsf(threshold[h])*0.1f;
    const float lk  = sigmoidf_(leak[h]);
    const float st  = softplusf_(steepness[h]);
    const float spr = softplusf_(ref_strength[h]);
    const float cw  = sigmoidf_(cross_w[h]);

    const size_t qoff = ((size_t)bh*1024 + g*64 + wave*16 + lx)*64;
    f16x8 aq0 = *(const f16x8*)(Qh + qoff + quad*8);
    f16x8 aq1 = *(const f16x8*)(Qh + qoff + 32 + quad*8);

    float mr[4], invl[4];
    #pragma unroll
    for (int r=0;r<4;r++){
        mr[r]   = rowm[(size_t)bh*1024 + g*64 + qpos + r];
        invl[r] = 1.f/rowl[(size_t)bh*1024 + g*64 + qpos + r];
    }

    f32x4 y[4];
    #pragma unroll
    for (int i=0;i<4;i++){ y[i][0]=0.f;y[i][1]=0.f;y[i][2]=0.f;y[i][3]=0.f; }
    float Dp[4] = {0.f,0.f,0.f,0.f};

    // phase 1
    for (int kt=0; kt<=g; kt++){
        __syncthreads();
        #pragma unroll
        for (int i=0;i<2;i++){
            int gi = i*256 + tid;
            int key = gi >> 3, kc = gi & 7;
            *(f16x8*)&Kl[kc*520 + key*8] =
                *(const f16x8*)(Kh + ((size_t)bh*1024 + kt*64 + key)*64 + kc*8);
            int d = gi >> 3;  // reuse indices: d in [0,64), kc chunk over t
            *(f16x8*)&Vl[kc*520 + d*8] =
                *(const f16x8*)(Vt + ((size_t)bh*64 + d)*1024 + kt*64 + kc*8);
        }
        if (tid < 64)
            ebase[tid] = thr + spr*colp[(size_t)bh*1024 + kt*64 + tid]*(1.0f/T_)
                             + cw*refr[(size_t)b*1024 + kt*64 + tid];
        __syncthreads();
        f32x4 sc[4];
        #pragma unroll
        for (int nt=0;nt<4;nt++){
            sc[nt][0]=0.f;sc[nt][1]=0.f;sc[nt][2]=0.f;sc[nt][3]=0.f;
            f16x8 b0 = *(const f16x8*)&Kl[quad*520     + (nt*16+lx)*8];
            f16x8 b1 = *(const f16x8*)&Kl[(4+quad)*520 + (nt*16+lx)*8];
            sc[nt] = MFMA16(aq0, b0, sc[nt]);
            sc[nt] = MFMA16(aq1, b1, sc[nt]);
        }
        const bool diag = (kt == g);
        #pragma unroll
        for (int nt=0;nt<4;nt++){
            float eb = ebase[nt*16+lx];
            #pragma unroll
            for (int r=0;r<4;r++){
                bool valid = !diag || ((nt*16+lx) <= (qpos + r));
                float pw = 0.f;
                if (valid){
                    float p = __expf(sc[nt][r]*SCALE_ - mr[r]) * invl[r];
                    float fire = sigmoidf_(st*(p - eb));
                    pw = p * (lk + (1.f-lk)*fire);
                    Dp[r] += pw;
                }
                Pl[wave][(quad*4+r)*72 + nt*16 + lx] = (f16)pw;
            }
        }
        __syncthreads();
        f16x8 ap0 = *(const f16x8*)&Pl[wave][lx*72 + quad*8];
        f16x8 ap1 = *(const f16x8*)&Pl[wave][lx*72 + 32 + quad*8];
        #pragma unroll
        for (int dt=0;dt<4;dt++){
            f16x8 bv0 = *(const f16x8*)&Vl[quad*520     + (dt*16+lx)*8];
            f16x8 bv1 = *(const f16x8*)&Vl[(4+quad)*520 + (dt*16+lx)*8];
            y[dt] = MFMA16(ap0, bv0, y[dt]);
            y[dt] = MFMA16(ap1, bv1, y[dt]);
        }
    }
    float invD[4];
    #pragma unroll
    for (int r=0;r<4;r++){
        float v = qsum_(Dp[r]);
        invD[r] = 1.f/(v + 1e-8f);
    }
    #pragma unroll
    for (int dt=0;dt<4;dt++){
        #pragma unroll
        for (int r=0;r<4;r++){
            Yh[(size_t)(b*1024 + g*64 + wave*16 + quad*4 + r)*1024 + h*64 + dt*16 + lx]
                = (f16)(y[dt][r]*invD[r]);
        }
    }

    // phase 2: column sums of mod
    for (int kt=0; kt<=g; kt++){
        __syncthreads();
        #pragma unroll
        for (int i=0;i<2;i++){
            int gi = i*256 + tid;
            int key = gi >> 3, kc = gi & 7;
            *(f16x8*)&Kl[kc*520 + key*8] =
                *(const f16x8*)(Kh + ((size_t)bh*1024 + kt*64 + key)*64 + kc*8);
        }
        if (tid < 64){
            ebase[tid] = thr + spr*colp[(size_t)bh*1024 + kt*64 + tid]*(1.0f/T_)
                             + cw*refr[(size_t)b*1024 + kt*64 + tid];
            colacc[tid] = 0.f;
        }
        __syncthreads();
        f32x4 sc[4];
        #pragma unroll
        for (int nt=0;nt<4;nt++){
            sc[nt][0]=0.f;sc[nt][1]=0.f;sc[nt][2]=0.f;sc[nt][3]=0.f;
            f16x8 b0 = *(const f16x8*)&Kl[quad*520     + (nt*16+lx)*8];
            f16x8 b1 = *(const f16x8*)&Kl[(4+quad)*520 + (nt*16+lx)*8];
            sc[nt] = MFMA16(aq0, b0, sc[nt]);
            sc[nt] = MFMA16(aq1, b1, sc[nt]);
        }
        const bool diag = (kt == g);
        float csum[4] = {0.f,0.f,0.f,0.f};
        #pragma unroll
        for (int nt=0;nt<4;nt++){
            float eb = ebase[nt*16+lx];
            #pragma unroll
            for (int r=0;r<4;r++){
                bool valid = !diag || ((nt*16+lx) <= (qpos + r));
                if (valid){
                    float p = __expf(sc[nt][r]*SCALE_ - mr[r]) * invl[r];
                    float fire = sigmoidf_(st*(p - eb));
                    csum[nt] += p * (lk + (1.f-lk)*fire) * invD[r];
                }
            }
        }
        #pragma unroll
        for (int nt=0;nt<4;nt++){
            float v = csum[nt];
            v += __shfl_xor(v,16,64); v += __shfl_xor(v,32,64);
            if (quad == 0) atomicAdd(&colacc[nt*16+lx], v);
        }
        __syncthreads();
        if (tid < 64) atomicAdd(&racc[(size_t)b*1024 + kt*64 + tid], colacc[tid]);
    }
}

__global__ __launch_bounds__(256) void finish_refr_k(
    const float* __restrict__ racc, float* __restrict__ out)
{
    int i = blockIdx.x*256 + threadIdx.x;
    if (i < B_*T_) out[i] = racc[i] * (1.0f/(H_*T_));
}

// ---------------------------------------------------------------------------
extern "C" void kernel_launch(void* const* d_in, const int* in_sizes, int n_in,
                              void* d_out, int out_size, void* d_ws, size_t ws_size,
                              hipStream_t stream) {
    (void)in_sizes; (void)n_in; (void)out_size; (void)ws_size;
    const float* x           = (const float*)d_in[0];
    const float* refr        = (const float*)d_in[1];
    const float* W_attn      = (const float*)d_in[2];
    const float* b_attn      = (const float*)d_in[3];
    const float* W_proj      = (const float*)d_in[4];
    const float* b_proj      = (const float*)d_in[5];
    const float* threshold   = (const float*)d_in[6];
    const float* leak        = (const float*)d_in[7];
    const float* steepness   = (const float*)d_in[8];
    const float* ref_strength= (const float*)d_in[9];
    const float* cross_w     = (const float*)d_in[10];
    float* out = (float*)d_out;

    char* ws = (char*)d_ws;
    f16* x_h = (f16*)ws;                       ws += (size_t)4096*1024*2;
    f16* WaT = (f16*)ws;                       ws += (size_t)3072*1024*2;
    f16* WpT = (f16*)ws;                       ws += (size_t)1024*1024*2;
    f16* Qh  = (f16*)ws;                       ws += (size_t)64*1024*64*2;
    f16* Kh  = (f16*)ws;                       ws += (size_t)64*1024*64*2;
    f16* Vt  = (f16*)ws;                       ws += (size_t)64*64*1024*2;
    f16* Yh  = (f16*)ws;                       ws += (size_t)4096*1024*2;
    float* rowm = (float*)ws;                  ws += (size_t)65536*4;
    float* rowl = (float*)ws;                  ws += (size_t)65536*4;
    float* colp = (float*)ws;                  ws += (size_t)65536*4;
    float* racc = (float*)ws;                  ws += (size_t)4096*4;

    hipMemsetAsync(colp, 0, 65536*sizeof(float), stream);
    hipMemsetAsync(racc, 0, 4096*sizeof(float), stream);

    conv_f16_k<<<dim3(2048), dim3(256), 0, stream>>>(x, x_h, 4096*1024/8);
    transpose_f16_k<<<dim3(96,32), dim3(256), 0, stream>>>(W_attn, WaT, 1024, 3072);
    transpose_f16_k<<<dim3(32,32), dim3(256), 0, stream>>>(W_proj, WpT, 1024, 1024);
    gemm_qkv_k<<<dim3(24,32), dim3(256), 0, stream>>>(x_h, WaT, b_attn, Qh, Kh, Vt);
    attn_stats_k<<<dim3(1024), dim3(256), 0, stream>>>(Qh, Kh, rowm, rowl, colp);
    attn_apply_k<<<dim3(1024), dim3(256), 0, stream>>>(
        Qh, Kh, Vt, rowm, rowl, colp, refr,
        threshold, leak, steepness, ref_strength, cross_w, Yh, racc);
    gemm_proj_k<<<dim3(8,32), dim3(256), 0, stream>>>(Yh, WpT, b_proj, out);
    finish_refr_k<<<dim3(16), dim3(256), 0, stream>>>(racc, out + (size_t)B_*T_*C_);
}

// Round 3
// 313.885 us; speedup vs baseline: 4.5381x; 1.0648x over previous
//
#include <hip/hip_runtime.h>
#include <math.h>

#define B_  4
#define T_  1024
#define C_  1024
#define H_  16
#define HS_ 64
#define K2E 0.1803368801f   // 0.125 * log2(e)
#define LOG2E 1.44269504f

typedef _Float16 f16;
typedef _Float16 f16x8 __attribute__((ext_vector_type(8)));
typedef float f32x4 __attribute__((ext_vector_type(4)));

#define MFMA16(a,b,c) __builtin_amdgcn_mfma_f32_16x16x32_f16(a,b,c,0,0,0)
#define EXP2(x) __builtin_amdgcn_exp2f(x)
#define RCP(x)  __builtin_amdgcn_rcpf(x)

__device__ __forceinline__ float qsum_(float v){
    v += __shfl_xor(v,1,64); v += __shfl_xor(v,2,64);
    v += __shfl_xor(v,4,64); v += __shfl_xor(v,8,64);
    return v;
}
__device__ __forceinline__ float sigmoidf_(float x){ return 1.0f/(1.0f + __expf(-x)); }
__device__ __forceinline__ float softplusf_(float x){ return fmaxf(x, 0.0f) + log1pf(__expf(-fabsf(x))); }

// ---------------------------------------------------------------------------
__global__ __launch_bounds__(256) void conv_f16_k(
    const float* __restrict__ in, f16* __restrict__ out, int n8)
{
    int i = blockIdx.x*256 + threadIdx.x;
    if (i < n8){
        const float4* p = (const float4*)in + (size_t)i*2;
        float4 a = p[0], b = p[1];
        f16x8 o;
        o[0]=(f16)a.x; o[1]=(f16)a.y; o[2]=(f16)a.z; o[3]=(f16)a.w;
        o[4]=(f16)b.x; o[5]=(f16)b.y; o[6]=(f16)b.z; o[7]=(f16)b.w;
        *((f16x8*)out + i) = o;
    }
}

__global__ __launch_bounds__(256) void transpose_f16_k(
    const float* __restrict__ in, f16* __restrict__ out, int K, int N)
{
    __shared__ float tl[32][33];
    const int n0 = blockIdx.x*32, k0 = blockIdx.y*32;
    const int c = threadIdx.x & 31, r4 = threadIdx.x >> 5;
    #pragma unroll
    for (int i=0;i<4;i++){
        int r = r4*4 + i;
        tl[r][c] = in[(size_t)(k0+r)*N + n0 + c];
    }
    __syncthreads();
    #pragma unroll
    for (int i=0;i<4;i++){
        int r = r4*4 + i;
        out[(size_t)(n0+r)*K + k0 + c] = (f16)tl[c][r];
    }
}

// ---------------------------------------------------------------------------
// GEMM qkv (unchanged from R2): 128x128x32 MFMA, scatter to Qh/Kh/Vt f16
// ---------------------------------------------------------------------------
__global__ __launch_bounds__(256) void gemm_qkv_k(
    const f16* __restrict__ A, const f16* __restrict__ Bt,
    const float* __restrict__ bias,
    f16* __restrict__ Qh, f16* __restrict__ Kh, f16* __restrict__ Vt)
{
    __shared__ __align__(16) f16 Al[4*1032];
    __shared__ __align__(16) f16 Bl[4*1032];
    const int tid = threadIdx.x;
    const int lane = tid & 63, wave = tid >> 6;
    const int lx = lane & 15, quad = lane >> 4;
    const int wm = wave & 1, wn = wave >> 1;
    const int m0 = blockIdx.y*128, n0 = blockIdx.x*128;
    f32x4 acc[4][4];
    #pragma unroll
    for (int i=0;i<4;i++){
        #pragma unroll
        for (int j=0;j<4;j++){ acc[i][j][0]=0.f;acc[i][j][1]=0.f;acc[i][j][2]=0.f;acc[i][j][3]=0.f; }
    }
    for (int k0=0; k0<1024; k0+=32){
        __syncthreads();
        #pragma unroll
        for (int i=0;i<2;i++){
            int g = i*256 + tid;
            int m = g >> 2, kc = g & 3;
            *(f16x8*)&Al[kc*1032 + m*8] = *(const f16x8*)(A  + (size_t)(m0+m)*1024 + k0 + kc*8);
            *(f16x8*)&Bl[kc*1032 + m*8] = *(const f16x8*)(Bt + (size_t)(n0+m)*1024 + k0 + kc*8);
        }
        __syncthreads();
        f16x8 af[4], bf[4];
        #pragma unroll
        for (int mt=0;mt<4;mt++) af[mt] = *(const f16x8*)&Al[quad*1032 + (wm*64+mt*16+lx)*8];
        #pragma unroll
        for (int nt=0;nt<4;nt++) bf[nt] = *(const f16x8*)&Bl[quad*1032 + (wn*64+nt*16+lx)*8];
        #pragma unroll
        for (int mt=0;mt<4;mt++){
            #pragma unroll
            for (int nt=0;nt<4;nt++)
                acc[mt][nt] = MFMA16(af[mt], bf[nt], acc[mt][nt]);
        }
    }
    #pragma unroll
    for (int mt=0;mt<4;mt++){
        #pragma unroll
        for (int nt=0;nt<4;nt++){
            int n = n0 + wn*64 + nt*16 + lx;
            int which = n >> 10, cc = n & 1023, h = cc >> 6, d = cc & 63;
            float bv = bias[n];
            #pragma unroll
            for (int r=0;r<4;r++){
                int m = m0 + wm*64 + mt*16 + quad*4 + r;
                int bb = m >> 10, t = m & 1023;
                int bh = bb*16 + h;
                float v = acc[mt][nt][r] + bv;
                if (which==0)      Qh[((size_t)bh*1024 + t)*64 + d] = (f16)v;
                else if (which==1) Kh[((size_t)bh*1024 + t)*64 + d] = (f16)v;
                else               Vt[((size_t)bh*64 + d)*1024 + t] = (f16)v;
            }
        }
    }
}

__global__ __launch_bounds__(256) void gemm_proj_k(
    const f16* __restrict__ A, const f16* __restrict__ Bt,
    const float* __restrict__ bias, float* __restrict__ out)
{
    __shared__ __align__(16) f16 Al[4*1032];
    __shared__ __align__(16) f16 Bl[4*1032];
    const int tid = threadIdx.x;
    const int lane = tid & 63, wave = tid >> 6;
    const int lx = lane & 15, quad = lane >> 4;
    const int wm = wave & 1, wn = wave >> 1;
    const int m0 = blockIdx.y*128, n0 = blockIdx.x*128;
    f32x4 acc[4][4];
    #pragma unroll
    for (int i=0;i<4;i++){
        #pragma unroll
        for (int j=0;j<4;j++){ acc[i][j][0]=0.f;acc[i][j][1]=0.f;acc[i][j][2]=0.f;acc[i][j][3]=0.f; }
    }
    for (int k0=0; k0<1024; k0+=32){
        __syncthreads();
        #pragma unroll
        for (int i=0;i<2;i++){
            int g = i*256 + tid;
            int m = g >> 2, kc = g & 3;
            *(f16x8*)&Al[kc*1032 + m*8] = *(const f16x8*)(A  + (size_t)(m0+m)*1024 + k0 + kc*8);
            *(f16x8*)&Bl[kc*1032 + m*8] = *(const f16x8*)(Bt + (size_t)(n0+m)*1024 + k0 + kc*8);
        }
        __syncthreads();
        f16x8 af[4], bf[4];
        #pragma unroll
        for (int mt=0;mt<4;mt++) af[mt] = *(const f16x8*)&Al[quad*1032 + (wm*64+mt*16+lx)*8];
        #pragma unroll
        for (int nt=0;nt<4;nt++) bf[nt] = *(const f16x8*)&Bl[quad*1032 + (wn*64+nt*16+lx)*8];
        #pragma unroll
        for (int mt=0;mt<4;mt++){
            #pragma unroll
            for (int nt=0;nt<4;nt++)
                acc[mt][nt] = MFMA16(af[mt], bf[nt], acc[mt][nt]);
        }
    }
    #pragma unroll
    for (int mt=0;mt<4;mt++){
        #pragma unroll
        for (int nt=0;nt<4;nt++){
            int n = n0 + wn*64 + nt*16 + lx;
            float bv = bias[n];
            #pragma unroll
            for (int r=0;r<4;r++){
                int m = m0 + wm*64 + mt*16 + quad*4 + r;
                out[(size_t)m*1024 + n] = acc[mt][nt][r] + bv;
            }
        }
    }
}

// ---------------------------------------------------------------------------
// attn_stats: block handles q-tiles {p, 15-p} of one bh (uniform 17 kt iters).
// No max subtraction. Sweep1: row sums l. Sweep2: column sums of p -> colp.
// ---------------------------------------------------------------------------
__global__ __launch_bounds__(256) void attn_stats_k(
    const f16* __restrict__ Qh, const f16* __restrict__ Kh,
    float* __restrict__ rowl, float* __restrict__ colp)
{
    __shared__ __align__(16) f16 Kl[8*520];
    __shared__ float colacc[64];
    const int tid = threadIdx.x;
    const int lane = tid & 63, wave = tid >> 6;
    const int lx = lane & 15, quad = lane >> 4;
    const int pair = blockIdx.x >> 6;
    const int bh = blockIdx.x & 63;
    const int qpos = wave*16 + quad*4;

    #pragma unroll 1
    for (int gi=0; gi<2; gi++){
        const int g = gi ? (15-pair) : pair;
        const size_t qoff = ((size_t)bh*1024 + g*64 + wave*16 + lx)*64;
        f16x8 aq0 = *(const f16x8*)(Qh + qoff + quad*8);
        f16x8 aq1 = *(const f16x8*)(Qh + qoff + 32 + quad*8);

        float ls[4] = {0.f,0.f,0.f,0.f};
        for (int kt=0; kt<=g; kt++){
            __syncthreads();
            #pragma unroll
            for (int i=0;i<2;i++){
                int gix = i*256 + tid;
                int key = gix >> 3, kc = gix & 7;
                *(f16x8*)&Kl[kc*520 + key*8] =
                    *(const f16x8*)(Kh + ((size_t)bh*1024 + kt*64 + key)*64 + kc*8);
            }
            __syncthreads();
            const bool diag = (kt == g);
            #pragma unroll
            for (int nt=0;nt<4;nt++){
                f32x4 sc = {0.f,0.f,0.f,0.f};
                f16x8 b0 = *(const f16x8*)&Kl[quad*520     + (nt*16+lx)*8];
                f16x8 b1 = *(const f16x8*)&Kl[(4+quad)*520 + (nt*16+lx)*8];
                sc = MFMA16(aq0, b0, sc);
                sc = MFMA16(aq1, b1, sc);
                #pragma unroll
                for (int r=0;r<4;r++){
                    float sv = sc[r];
                    if (diag && (nt*16+lx) > (qpos + r)) sv = -1e4f;
                    ls[r] += EXP2(sv*K2E);
                }
            }
        }
        float invl[4];
        #pragma unroll
        for (int r=0;r<4;r++){
            float l = qsum_(ls[r]);
            if (lx == 0) rowl[(size_t)bh*1024 + g*64 + qpos + r] = l;
            invl[r] = RCP(l);
        }

        for (int kt=0; kt<=g; kt++){
            __syncthreads();
            #pragma unroll
            for (int i=0;i<2;i++){
                int gix = i*256 + tid;
                int key = gix >> 3, kc = gix & 7;
                *(f16x8*)&Kl[kc*520 + key*8] =
                    *(const f16x8*)(Kh + ((size_t)bh*1024 + kt*64 + key)*64 + kc*8);
            }
            if (tid < 64) colacc[tid] = 0.f;
            __syncthreads();
            const bool diag = (kt == g);
            #pragma unroll
            for (int nt=0;nt<4;nt++){
                f32x4 sc = {0.f,0.f,0.f,0.f};
                f16x8 b0 = *(const f16x8*)&Kl[quad*520     + (nt*16+lx)*8];
                f16x8 b1 = *(const f16x8*)&Kl[(4+quad)*520 + (nt*16+lx)*8];
                sc = MFMA16(aq0, b0, sc);
                sc = MFMA16(aq1, b1, sc);
                float csum = 0.f;
                #pragma unroll
                for (int r=0;r<4;r++){
                    float sv = sc[r];
                    if (diag && (nt*16+lx) > (qpos + r)) sv = -1e4f;
                    csum += EXP2(sv*K2E) * invl[r];
                }
                csum += __shfl_xor(csum,16,64); csum += __shfl_xor(csum,32,64);
                if (quad == 0) atomicAdd(&colacc[nt*16+lx], csum);
            }
            __syncthreads();
            if (tid < 64) atomicAdd(&colp[(size_t)bh*1024 + kt*64 + tid], colacc[tid]);
        }
    }
}

// ---------------------------------------------------------------------------
// attn_apply: block handles q-tiles {p, 15-p} of one bh. eff_thr base cached
// for all 1024 keys in LDS. Sweep1: pw, D, PV -> Yh. Sweep2: racc.
// ---------------------------------------------------------------------------
__global__ __launch_bounds__(256) void attn_apply_k(
    const f16* __restrict__ Qh, const f16* __restrict__ Kh, const f16* __restrict__ Vt,
    const float* __restrict__ rowl,
    const float* __restrict__ colp, const float* __restrict__ refr,
    const float* __restrict__ threshold, const float* __restrict__ leak,
    const float* __restrict__ steepness, const float* __restrict__ ref_strength,
    const float* __restrict__ cross_w,
    f16* __restrict__ Yh, float* __restrict__ racc)
{
    __shared__ __align__(16) f16 Kl[8*520];
    __shared__ __align__(16) f16 Vl[8*520];
    __shared__ __align__(16) f16 Pl[4][16*72];
    __shared__ float eb[1024];
    __shared__ float colacc[64];
    const int tid = threadIdx.x;
    const int lane = tid & 63, wave = tid >> 6;
    const int lx = lane & 15, quad = lane >> 4;
    const int pair = blockIdx.x >> 6;
    const int bh = blockIdx.x & 63;
    const int b  = bh >> 4, h = bh & 15;
    const int qpos = wave*16 + quad*4;

    const float thr = fabsf(threshold[h])*0.1f;
    const float lk  = sigmoidf_(leak[h]);
    const float st2 = softplusf_(steepness[h]) * LOG2E;
    const float sprT= softplusf_(ref_strength[h]) * (1.0f/T_);
    const float cw  = sigmoidf_(cross_w[h]);
    const float Alk = 1.f - lk;

    // stage eff_thr base for all keys once
    {
        float4 cp = *(const float4*)(colp + (size_t)bh*1024 + tid*4);
        float4 rf = *(const float4*)(refr + (size_t)b*1024 + tid*4);
        eb[tid*4+0] = thr + sprT*cp.x + cw*rf.x;
        eb[tid*4+1] = thr + sprT*cp.y + cw*rf.y;
        eb[tid*4+2] = thr + sprT*cp.z + cw*rf.z;
        eb[tid*4+3] = thr + sprT*cp.w + cw*rf.w;
    }

    #pragma unroll 1
    for (int gi=0; gi<2; gi++){
        const int g = gi ? (15-pair) : pair;
        const size_t qoff = ((size_t)bh*1024 + g*64 + wave*16 + lx)*64;
        f16x8 aq0 = *(const f16x8*)(Qh + qoff + quad*8);
        f16x8 aq1 = *(const f16x8*)(Qh + qoff + 32 + quad*8);

        float invl[4];
        #pragma unroll
        for (int r=0;r<4;r++)
            invl[r] = RCP(rowl[(size_t)bh*1024 + g*64 + qpos + r]);

        f32x4 y[4];
        #pragma unroll
        for (int i=0;i<4;i++){ y[i][0]=0.f;y[i][1]=0.f;y[i][2]=0.f;y[i][3]=0.f; }
        float Dp[4] = {0.f,0.f,0.f,0.f};

        // sweep 1: pw, D, PV
        for (int kt=0; kt<=g; kt++){
            __syncthreads();
            #pragma unroll
            for (int i=0;i<2;i++){
                int gix = i*256 + tid;
                int key = gix >> 3, kc = gix & 7;
                *(f16x8*)&Kl[kc*520 + key*8] =
                    *(const f16x8*)(Kh + ((size_t)bh*1024 + kt*64 + key)*64 + kc*8);
                *(f16x8*)&Vl[kc*520 + key*8] =
                    *(const f16x8*)(Vt + ((size_t)bh*64 + key)*1024 + kt*64 + kc*8);
            }
            __syncthreads();
            const bool diag = (kt == g);
            #pragma unroll
            for (int nt=0;nt<4;nt++){
                f32x4 sc = {0.f,0.f,0.f,0.f};
                f16x8 b0 = *(const f16x8*)&Kl[quad*520     + (nt*16+lx)*8];
                f16x8 b1 = *(const f16x8*)&Kl[(4+quad)*520 + (nt*16+lx)*8];
                sc = MFMA16(aq0, b0, sc);
                sc = MFMA16(aq1, b1, sc);
                float ec = st2 * eb[kt*64 + nt*16 + lx];
                #pragma unroll
                for (int r=0;r<4;r++){
                    float sv = sc[r];
                    if (diag && (nt*16+lx) > (qpos + r)) sv = -1e4f;
                    float p = EXP2(sv*K2E) * invl[r];
                    float e2 = EXP2(ec - st2*p);
                    float fire = RCP(1.f + e2);
                    float pw = p * (lk + Alk*fire);
                    Dp[r] += pw;
                    Pl[wave][(quad*4+r)*72 + nt*16 + lx] = (f16)pw;
                }
            }
            __syncthreads();
            f16x8 ap0 = *(const f16x8*)&Pl[wave][lx*72 + quad*8];
            f16x8 ap1 = *(const f16x8*)&Pl[wave][lx*72 + 32 + quad*8];
            #pragma unroll
            for (int dt=0;dt<4;dt++){
                f16x8 bv0 = *(const f16x8*)&Vl[quad*520     + (dt*16+lx)*8];
                f16x8 bv1 = *(const f16x8*)&Vl[(4+quad)*520 + (dt*16+lx)*8];
                y[dt] = MFMA16(ap0, bv0, y[dt]);
                y[dt] = MFMA16(ap1, bv1, y[dt]);
            }
        }
        float invD[4];
        #pragma unroll
        for (int r=0;r<4;r++) invD[r] = RCP(qsum_(Dp[r]) + 1e-8f);
        #pragma unroll
        for (int dt=0;dt<4;dt++){
            #pragma unroll
            for (int r=0;r<4;r++){
                Yh[(size_t)(b*1024 + g*64 + wave*16 + quad*4 + r)*1024 + h*64 + dt*16 + lx]
                    = (f16)(y[dt][r]*invD[r]);
            }
        }

        // sweep 2: column sums of mod
        for (int kt=0; kt<=g; kt++){
            __syncthreads();
            #pragma unroll
            for (int i=0;i<2;i++){
                int gix = i*256 + tid;
                int key = gix >> 3, kc = gix & 7;
                *(f16x8*)&Kl[kc*520 + key*8] =
                    *(const f16x8*)(Kh + ((size_t)bh*1024 + kt*64 + key)*64 + kc*8);
            }
            if (tid < 64) colacc[tid] = 0.f;
            __syncthreads();
            const bool diag = (kt == g);
            #pragma unroll
            for (int nt=0;nt<4;nt++){
                f32x4 sc = {0.f,0.f,0.f,0.f};
                f16x8 b0 = *(const f16x8*)&Kl[quad*520     + (nt*16+lx)*8];
                f16x8 b1 = *(const f16x8*)&Kl[(4+quad)*520 + (nt*16+lx)*8];
                sc = MFMA16(aq0, b0, sc);
                sc = MFMA16(aq1, b1, sc);
                float ec = st2 * eb[kt*64 + nt*16 + lx];
                float csum = 0.f;
                #pragma unroll
                for (int r=0;r<4;r++){
                    float sv = sc[r];
                    if (diag && (nt*16+lx) > (qpos + r)) sv = -1e4f;
                    float p = EXP2(sv*K2E) * invl[r];
                    float e2 = EXP2(ec - st2*p);
                    float fire = RCP(1.f + e2);
                    csum += p * (lk + Alk*fire) * invD[r];
                }
                csum += __shfl_xor(csum,16,64); csum += __shfl_xor(csum,32,64);
                if (quad == 0) atomicAdd(&colacc[nt*16+lx], csum);
            }
            __syncthreads();
            if (tid < 64) atomicAdd(&racc[(size_t)b*1024 + kt*64 + tid], colacc[tid]);
        }
    }
}

__global__ __launch_bounds__(256) void finish_refr_k(
    const float* __restrict__ racc, float* __restrict__ out)
{
    int i = blockIdx.x*256 + threadIdx.x;
    if (i < B_*T_) out[i] = racc[i] * (1.0f/(H_*T_));
}

// ---------------------------------------------------------------------------
extern "C" void kernel_launch(void* const* d_in, const int* in_sizes, int n_in,
                              void* d_out, int out_size, void* d_ws, size_t ws_size,
                              hipStream_t stream) {
    (void)in_sizes; (void)n_in; (void)out_size; (void)ws_size;
    const float* x           = (const float*)d_in[0];
    const float* refr        = (const float*)d_in[1];
    const float* W_attn      = (const float*)d_in[2];
    const float* b_attn      = (const float*)d_in[3];
    const float* W_proj      = (const float*)d_in[4];
    const float* b_proj      = (const float*)d_in[5];
    const float* threshold   = (const float*)d_in[6];
    const float* leak        = (const float*)d_in[7];
    const float* steepness   = (const float*)d_in[8];
    const float* ref_strength= (const float*)d_in[9];
    const float* cross_w     = (const float*)d_in[10];
    float* out = (float*)d_out;

    char* ws = (char*)d_ws;
    f16* x_h = (f16*)ws;                       ws += (size_t)4096*1024*2;
    f16* WaT = (f16*)ws;                       ws += (size_t)3072*1024*2;
    f16* WpT = (f16*)ws;                       ws += (size_t)1024*1024*2;
    f16* Qh  = (f16*)ws;                       ws += (size_t)64*1024*64*2;
    f16* Kh  = (f16*)ws;                       ws += (size_t)64*1024*64*2;
    f16* Vt  = (f16*)ws;                       ws += (size_t)64*64*1024*2;
    f16* Yh  = (f16*)ws;                       ws += (size_t)4096*1024*2;
    float* rowl = (float*)ws;                  ws += (size_t)65536*4;
    float* colp = (float*)ws;                  ws += (size_t)65536*4;
    float* racc = (float*)ws;                  ws += (size_t)4096*4;

    hipMemsetAsync(colp, 0, 65536*sizeof(float), stream);
    hipMemsetAsync(racc, 0, 4096*sizeof(float), stream);

    conv_f16_k<<<dim3(2048), dim3(256), 0, stream>>>(x, x_h, 4096*1024/8);
    transpose_f16_k<<<dim3(96,32), dim3(256), 0, stream>>>(W_attn, WaT, 1024, 3072);
    transpose_f16_k<<<dim3(32,32), dim3(256), 0, stream>>>(W_proj, WpT, 1024, 1024);
    gemm_qkv_k<<<dim3(24,32), dim3(256), 0, stream>>>(x_h, WaT, b_attn, Qh, Kh, Vt);
    attn_stats_k<<<dim3(512), dim3(256), 0, stream>>>(Qh, Kh, rowl, colp);
    attn_apply_k<<<dim3(512), dim3(256), 0, stream>>>(
        Qh, Kh, Vt, rowl, colp, refr,
        threshold, leak, steepness, ref_strength, cross_w, Yh, racc);
    gemm_proj_k<<<dim3(8,32), dim3(256), 0, stream>>>(Yh, WpT, b_proj, out);
    finish_refr_k<<<dim3(16), dim3(256), 0, stream>>>(racc, out + (size_t)B_*T_*C_);
}